// Round 13
// baseline (5964.782 us; speedup 1.0000x reference)
//
#include <hip/hip_runtime.h>
#include <hip/hip_bf16.h>

#define S_LEN 2048
#define BATCH 8
#define HID   1024
#define NP    3072      // permuted gate dim: i,g,o only (f is dead in reference)
#define MROWS 16384     // S*B

using bf16x8 = __attribute__((ext_vector_type(8))) short;
using f32x4  = __attribute__((ext_vector_type(4))) float;

__device__ __forceinline__ unsigned short f2b(float f) {
  unsigned int u = __builtin_bit_cast(unsigned int, f);
  u += 0x7fffu + ((u >> 16) & 1u);   // RNE
  return (unsigned short)(u >> 16);
}

__device__ __forceinline__ float sigf(float x) {
  return 1.f / (1.f + __expf(-x));
}
__device__ __forceinline__ float tanh_f(float x) {
  return 2.f / (1.f + __expf(-2.f * x)) - 1.f;   // exact limits at +-inf
}

__device__ __forceinline__ void load_lds16(const void* g, void* l) {
  __builtin_amdgcn_global_load_lds(
      (const __attribute__((address_space(1))) void*)g,
      (__attribute__((address_space(3))) void*)(unsigned int)(unsigned long long)l,
      16, 0, 0);
}

#define MEMFENCE asm volatile("" ::: "memory")
#define BARRIER  do { MEMFENCE; __builtin_amdgcn_s_barrier(); MEMFENCE; } while (0)
#define LGKM0    asm volatile("s_waitcnt lgkmcnt(0)" ::: "memory")

// ---- fused prep: x cvt + 4 weight permutes + 4 bias permutes (one launch).
//  Weight layout (R3-verified): Wp[np][k], np = chunk*48 + gate3*16 + hl,
//  gate3 {0:i,1:g,2:o} -> orig rows {0,2,3}*1024 + chunk*16 + hl. ----
__device__ __forceinline__ void permute_w_dev(const float* __restrict__ W,
                                              unsigned short* __restrict__ Wp,
                                              long id, int K) {
  const long i = id * 4;
  const int np = (int)(i / K);
  const int k0 = (int)(i % K);
  const int chunk = np / 48, rem = np % 48;
  const int g3 = rem >> 4, hl = rem & 15;
  const int og = (g3 == 0) ? 0 : (g3 == 1) ? 2 : 3;
  const int n  = og * 1024 + chunk * 16 + hl;
  const float4 v = *reinterpret_cast<const float4*>(W + (long)n * K + k0);
  ushort4 u;
  u.x = f2b(v.x); u.y = f2b(v.y); u.z = f2b(v.z); u.w = f2b(v.w);
  *reinterpret_cast<ushort4*>(Wp + i) = u;
}

__global__ void prep(const float* __restrict__ x, unsigned short* __restrict__ x_bf,
                     const float* __restrict__ Wf0, const float* __restrict__ Wb0,
                     const float* __restrict__ Wf1, const float* __restrict__ Wb1,
                     unsigned short* __restrict__ pf0, unsigned short* __restrict__ pb0,
                     unsigned short* __restrict__ pf1, unsigned short* __restrict__ pb1,
                     const float* __restrict__ bf0, const float* __restrict__ bb0,
                     const float* __restrict__ bf1, const float* __restrict__ bb1,
                     float* __restrict__ bpf0, float* __restrict__ bpb0,
                     float* __restrict__ bpf1, float* __restrict__ bpb1) {
  const int blk = blockIdx.x;
  const int tid = threadIdx.x;
  if (blk < 16384) {               // x: fp32 -> bf16, float4/thread (exact)
    const int i = blk * 256 + tid;
    const float4 v = reinterpret_cast<const float4*>(x)[i];
    ushort4 u;
    u.x = f2b(v.x); u.y = f2b(v.y); u.z = f2b(v.z); u.w = f2b(v.w);
    reinterpret_cast<ushort4*>(x_bf)[i] = u;
  } else if (blk < 19456) {
    permute_w_dev(Wf0, pf0, (long)(blk - 16384) * 256 + tid, 1024);
  } else if (blk < 22528) {
    permute_w_dev(Wb0, pb0, (long)(blk - 19456) * 256 + tid, 1024);
  } else if (blk < 28672) {
    permute_w_dev(Wf1, pf1, (long)(blk - 22528) * 256 + tid, 2048);
  } else if (blk < 34816) {
    permute_w_dev(Wb1, pb1, (long)(blk - 28672) * 256 + tid, 2048);
  } else {                         // biases: np = chunk*48 + gate3*16 + hl
    const int r = blk - 34816;     // 0..47
    const int which = r / 12;
    const int np = (r % 12) * 256 + tid;
    const float* bs = which == 0 ? bf0 : which == 1 ? bb0 : which == 2 ? bf1 : bb1;
    float* bd       = which == 0 ? bpf0 : which == 1 ? bpb0 : which == 2 ? bpf1 : bpb1;
    const int chunk = np / 48, rem = np % 48;
    const int g3 = rem >> 4, hl = rem & 15;
    const int og = (g3 == 0) ? 0 : (g3 == 1) ? 2 : 3;
    bd[np] = bs[og * 1024 + chunk * 16 + hl];
  }
}

// ---- fused GEMM + gates, SINGLE-buffered for 4 blocks/CU residency.
//  C = A[M,K] * Wp[NP,K]^T.  Block tile 128x192, BK=64, 256 thr (4 waves 2Mx2N).
//  Wave tile 64x96 = 4 m-frags x 6 n-frags (2 h-chunks x {i,g,o}) = 48 MFMA/tile.
//  LDS: ONE 40KB buffer (A 128x64 @0, B 192x64 @16384) -> 4 blocks/CU; the
//  cross-block async overlap (m114) hides what double-buffering couldn't.
//  K-loop: 20 ds_reads -> lgkm0+barrier (reads reg-complete block-wide) ->
//  STAGE(t+1) overwrites buf -> 48 MFMA (hides stage latency) -> vmcnt0+barrier.
template <int MODE>  // 0: layer0 (bf16 out), 1: layer1 (fp32 out to d_out)
__global__ void __launch_bounds__(256, 4)
lstm_gemm(const unsigned short* __restrict__ A,
          const unsigned short* __restrict__ WpF,
          const unsigned short* __restrict__ WpB,
          const float* __restrict__ bpF, const float* __restrict__ bpB,
          int K,
          unsigned short* __restrict__ out_bf, float* __restrict__ out_f,
          float* __restrict__ hn, float* __restrict__ cn) {
  __shared__ __align__(16) char lds[40960];

  const int dir = blockIdx.z;
  const unsigned short* __restrict__ Wp = dir ? WpB : WpF;
  const float* __restrict__ bp = dir ? bpB : bpF;
  const int bn = blockIdx.x;   // 0..15  (192-col band of Wp)
  const int bm = blockIdx.y;   // 0..127 (128-row band of A)

  const int tid  = threadIdx.x;
  const int wid  = tid >> 6;
  const int lane = tid & 63;
  const int wm   = wid >> 1;   // 0..1
  const int wn   = wid & 1;    // 0..1

  const int  nt = K >> 6;
  const long K2 = (long)K * 2;

  // ---- staging constants (linear LDS dest, pre-swizzled global source).
  //  Slot = 8 rows x 128B = 1KB, written by one global_load_lds of one wave.
  //  LDS (row, c16) holds global (row, c16 ^ (row&7)).
  const int rlane = lane >> 3;                       // row within slot 0..7
  const int cb    = (((lane & 7) ^ rlane) << 4);     // pre-swizzled col byte
  const char* Asrc = (const char*)A  + ((long)bm * 128 + rlane) * K2 + cb;
  const char* Bsrc = (const char*)Wp + ((long)bn * 192 + rlane) * K2 + cb;

  // ---- compute-side constants (swizzled ds_read) ----
  const int l15 = lane & 15;
  const int hi  = lane >> 4;                  // 0..3
  const int c0  = ((hi ^ (l15 & 7)) << 4);    // kh0 chunk; kh1 = c0 ^ 64
  const int aro = (wm * 64 + l15) * 128;            // + mf*2048
  const int bro = 16384 + (wn * 96 + l15) * 128;    // + nf*2048

  f32x4 acc[4][6];
  const f32x4 zero = {0.f, 0.f, 0.f, 0.f};
#pragma unroll
  for (int i = 0; i < 4; ++i)
#pragma unroll
    for (int j = 0; j < 6; ++j) acc[i][j] = zero;

  auto STAGE = [&](int t) {   // 10 x global_load_lds per thread
    if (t >= nt) return;
    const long off = (long)t * 128;   // 64 bf16 = 128 B per K-tile
#pragma unroll
    for (int s = 0; s < 4; ++s) {
      const int slot = s * 4 + wid;   // 0..15 -> A rows slot*8..slot*8+7
      load_lds16(Asrc + (long)(slot * 8) * K2 + off, lds + slot * 1024);
    }
#pragma unroll
    for (int s = 0; s < 6; ++s) {
      const int slot = s * 4 + wid;   // 0..23 -> B rows slot*8..slot*8+7
      load_lds16(Bsrc + (long)(slot * 8) * K2 + off, lds + 16384 + slot * 1024);
    }
  };

  STAGE(0);
  asm volatile("s_waitcnt vmcnt(0)" ::: "memory");
  BARRIER;

  for (int t = 0; t < nt; ++t) {
    // read tile t fragments into registers
    bf16x8 a[4][2], b[6][2];
#pragma unroll
    for (int nf = 0; nf < 6; ++nf) {
      b[nf][0] = *(const bf16x8*)(lds + bro + nf * 2048 + c0);
      b[nf][1] = *(const bf16x8*)(lds + bro + nf * 2048 + (c0 ^ 64));
    }
#pragma unroll
    for (int mf = 0; mf < 4; ++mf) {
      a[mf][0] = *(const bf16x8*)(lds + aro + mf * 2048 + c0);
      a[mf][1] = *(const bf16x8*)(lds + aro + mf * 2048 + (c0 ^ 64));
    }
    LGKM0;      // own reads register-complete
    BARRIER;    // all waves' reads complete -> safe to overwrite buffer

    STAGE(t + 1);   // overwrite; latency hidden under the MFMA cluster below

    __builtin_amdgcn_s_setprio(1);
#pragma unroll
    for (int mf = 0; mf < 4; ++mf)
#pragma unroll
      for (int nf = 0; nf < 6; ++nf) {
        acc[mf][nf] = __builtin_amdgcn_mfma_f32_16x16x32_bf16(
            a[mf][0], b[nf][0], acc[mf][nf], 0, 0, 0);
        acc[mf][nf] = __builtin_amdgcn_mfma_f32_16x16x32_bf16(
            a[mf][1], b[nf][1], acc[mf][nf], 0, 0, 0);
      }
    __builtin_amdgcn_s_setprio(0);

    asm volatile("s_waitcnt vmcnt(0)" ::: "memory");   // tile t+1 resident
    BARRIER;
  }

  // ---- epilogue: gates -> h (and h_n/c_n rows) ----
  const int col    = l15;
  const int rbase  = hi * 4;
  const int chunk0 = bn * 4 + wn * 2;
  const int Lidx   = MODE * 2 + dir;

#pragma unroll
  for (int hg = 0; hg < 2; ++hg) {
    const int chunk  = chunk0 + hg;
    const int h      = chunk * 16 + col;
    const int outcol = dir * HID + h;
    const float bi = bp[chunk * 48 + col];
    const float bg = bp[chunk * 48 + 16 + col];
    const float bo = bp[chunk * 48 + 32 + col];
#pragma unroll
    for (int mf = 0; mf < 4; ++mf) {
#pragma unroll
      for (int r = 0; r < 4; ++r) {
        const int m = bm * 128 + wm * 64 + mf * 16 + rbase + r;
        const float iv = acc[mf][hg * 3 + 0][r] + bi;
        const float gv = acc[mf][hg * 3 + 1][r] + bg;
        const float ov = acc[mf][hg * 3 + 2][r] + bo;
        const float is = sigf(iv);
        const float gt = tanh_f(gv);
        const float os = sigf(ov);
        const float c  = is * gt;
        const float hv = os * tanh_f(c);
        if (MODE == 0) {
          out_bf[(long)m * 2048 + outcol] = f2b(hv);
        } else {
          out_f[(long)m * 2048 + outcol] = hv;
        }
        const bool wst = (dir == 0) ? (m >= (S_LEN - 1) * BATCH) : (m < BATCH);
        if (wst) {
          const int b = (dir == 0) ? (m - (S_LEN - 1) * BATCH) : m;
          hn[((long)Lidx * BATCH + b) * HID + h] = hv;
          cn[((long)Lidx * BATCH + b) * HID + h] = c;
        }
      }
    }
  }
}

extern "C" void kernel_launch(void* const* d_in, const int* in_sizes, int n_in,
                              void* d_out, int out_size, void* d_ws, size_t ws_size,
                              hipStream_t stream) {
  const float* x    = (const float*)d_in[0];
  const float* W_f0 = (const float*)d_in[1];
  const float* b_f0 = (const float*)d_in[2];
  const float* W_b0 = (const float*)d_in[3];
  const float* b_b0 = (const float*)d_in[4];
  const float* W_f1 = (const float*)d_in[5];
  const float* b_f1 = (const float*)d_in[6];
  const float* W_b1 = (const float*)d_in[7];
  const float* b_b1 = (const float*)d_in[8];

  float* out = (float*)d_out;
  float* hn  = out + (long)MROWS * 2048;
  float* cn  = hn + 4 * BATCH * HID;

  unsigned short* x_bf  = (unsigned short*)d_ws;
  unsigned short* out1  = x_bf + (long)MROWS * 1024;
  unsigned short* wp_f0 = out1 + (long)MROWS * 2048;
  unsigned short* wp_b0 = wp_f0 + (long)NP * 1024;
  unsigned short* wp_f1 = wp_b0 + (long)NP * 1024;
  unsigned short* wp_b1 = wp_f1 + (long)NP * 2048;
  float* bp_f0 = (float*)(wp_b1 + (long)NP * 2048);
  float* bp_b0 = bp_f0 + NP;
  float* bp_f1 = bp_b0 + NP;
  float* bp_b1 = bp_f1 + NP;

  prep<<<34864, 256, 0, stream>>>(x, x_bf, W_f0, W_b0, W_f1, W_b1,
                                  wp_f0, wp_b0, wp_f1, wp_b1,
                                  b_f0, b_b0, b_f1, b_b1,
                                  bp_f0, bp_b0, bp_f1, bp_b1);

  dim3 grid(16, 128, 2);
  lstm_gemm<0><<<grid, 256, 0, stream>>>(x_bf, wp_f0, wp_b0, bp_f0, bp_b0, 1024,
                                         out1, nullptr, hn, cn);
  lstm_gemm<1><<<grid, 256, 0, stream>>>(out1, wp_f1, wp_b1, bp_f1, bp_b1, 2048,
                                         nullptr, out, hn, cn);
}

// Round 14
// 652.587 us; speedup vs baseline: 9.1402x; 9.1402x over previous
//
#include <hip/hip_runtime.h>
#include <hip/hip_bf16.h>

#define S_LEN 2048
#define BATCH 8
#define HID   1024
#define NP    3072      // permuted gate dim: i,g,o only (f is dead in reference)
#define MROWS 16384     // S*B

using bf16x8 = __attribute__((ext_vector_type(8))) short;
using f32x4  = __attribute__((ext_vector_type(4))) float;

__device__ __forceinline__ unsigned short f2b(float f) {
  unsigned int u = __builtin_bit_cast(unsigned int, f);
  u += 0x7fffu + ((u >> 16) & 1u);   // RNE
  return (unsigned short)(u >> 16);
}

__device__ __forceinline__ float sigf(float x) {
  return 1.f / (1.f + __expf(-x));
}
__device__ __forceinline__ float tanh_f(float x) {
  return 2.f / (1.f + __expf(-2.f * x)) - 1.f;   // exact limits at +-inf
}

__device__ __forceinline__ void load_lds16(const void* g, void* l) {
  __builtin_amdgcn_global_load_lds(
      (const __attribute__((address_space(1))) void*)g,
      (__attribute__((address_space(3))) void*)(unsigned int)(unsigned long long)l,
      16, 0, 0);
}

#define MEMFENCE asm volatile("" ::: "memory")
#define BARRIER  do { MEMFENCE; __builtin_amdgcn_s_barrier(); MEMFENCE; } while (0)
#define LGKM0    asm volatile("s_waitcnt lgkmcnt(0)" ::: "memory")
#define VM0      asm volatile("s_waitcnt vmcnt(0)" ::: "memory")
#define SB       __builtin_amdgcn_sched_barrier(0)

// ---- fused prep: x cvt + 4 weight permutes + 4 bias permutes (one launch).
//  Weight layout (R3-verified): Wp[np][k], np = chunk*48 + gate3*16 + hl,
//  gate3 {0:i,1:g,2:o} -> orig rows {0,2,3}*1024 + chunk*16 + hl. ----
__device__ __forceinline__ void permute_w_dev(const float* __restrict__ W,
                                              unsigned short* __restrict__ Wp,
                                              long id, int K) {
  const long i = id * 4;
  const int np = (int)(i / K);
  const int k0 = (int)(i % K);
  const int chunk = np / 48, rem = np % 48;
  const int g3 = rem >> 4, hl = rem & 15;
  const int og = (g3 == 0) ? 0 : (g3 == 1) ? 2 : 3;
  const int n  = og * 1024 + chunk * 16 + hl;
  const float4 v = *reinterpret_cast<const float4*>(W + (long)n * K + k0);
  ushort4 u;
  u.x = f2b(v.x); u.y = f2b(v.y); u.z = f2b(v.z); u.w = f2b(v.w);
  *reinterpret_cast<ushort4*>(Wp + i) = u;
}

__global__ void prep(const float* __restrict__ x, unsigned short* __restrict__ x_bf,
                     const float* __restrict__ Wf0, const float* __restrict__ Wb0,
                     const float* __restrict__ Wf1, const float* __restrict__ Wb1,
                     unsigned short* __restrict__ pf0, unsigned short* __restrict__ pb0,
                     unsigned short* __restrict__ pf1, unsigned short* __restrict__ pb1,
                     const float* __restrict__ bf0, const float* __restrict__ bb0,
                     const float* __restrict__ bf1, const float* __restrict__ bb1,
                     float* __restrict__ bpf0, float* __restrict__ bpb0,
                     float* __restrict__ bpf1, float* __restrict__ bpb1) {
  const int blk = blockIdx.x;
  const int tid = threadIdx.x;
  if (blk < 16384) {               // x: fp32 -> bf16, float4/thread (exact)
    const int i = blk * 256 + tid;
    const float4 v = reinterpret_cast<const float4*>(x)[i];
    ushort4 u;
    u.x = f2b(v.x); u.y = f2b(v.y); u.z = f2b(v.z); u.w = f2b(v.w);
    reinterpret_cast<ushort4*>(x_bf)[i] = u;
  } else if (blk < 19456) {
    permute_w_dev(Wf0, pf0, (long)(blk - 16384) * 256 + tid, 1024);
  } else if (blk < 22528) {
    permute_w_dev(Wb0, pb0, (long)(blk - 19456) * 256 + tid, 1024);
  } else if (blk < 28672) {
    permute_w_dev(Wf1, pf1, (long)(blk - 22528) * 256 + tid, 2048);
  } else if (blk < 34816) {
    permute_w_dev(Wb1, pb1, (long)(blk - 28672) * 256 + tid, 2048);
  } else {                         // biases: np = chunk*48 + gate3*16 + hl
    const int r = blk - 34816;     // 0..47
    const int which = r / 12;
    const int np = (r % 12) * 256 + tid;
    const float* bs = which == 0 ? bf0 : which == 1 ? bb0 : which == 2 ? bf1 : bb1;
    float* bd       = which == 0 ? bpf0 : which == 1 ? bpb0 : which == 2 ? bpf1 : bpb1;
    const int chunk = np / 48, rem = np % 48;
    const int g3 = rem >> 4, hl = rem & 15;
    const int og = (g3 == 0) ? 0 : (g3 == 1) ? 2 : 3;
    bd[np] = bs[og * 1024 + chunk * 16 + hl];
  }
}

// ---- fused GEMM + gates, half-tile software-pipelined (R12 resources).
//  C = A[M,K] * Wp[NP,K]^T.  Block tile 128x192, BK=64, 256 thr (4 waves 2Mx2N).
//  Wave tile 64x96 = 4 m-frags x 6 n-frags = 48 MFMA/tile in two 24-clusters.
//  LDS: 2 buffers x 40KB -> 80KB -> 2 blocks/CU.  Per tile:
//  STAGE(t+1) -> R(t,kh0)->P -> MFMA(t-1,kh1|Q) -> R(t,kh1)->Q ->
//  MFMA(t,kh0|P) -> lgkm0 -> vmcnt0 -> barrier.  Every read burst is covered
//  by an MFMA cluster (R12 counters: MFMA 50% + LDS 52% = 100% of wall, zero
//  pipe overlap from the reads-then-MFMA phase lock; this breaks the lock).
template <int MODE>  // 0: layer0 (bf16 out), 1: layer1 (fp32 out to d_out)
__global__ void __launch_bounds__(256, 2)
lstm_gemm(const unsigned short* __restrict__ A,
          const unsigned short* __restrict__ WpF,
          const unsigned short* __restrict__ WpB,
          const float* __restrict__ bpF, const float* __restrict__ bpB,
          int K,
          unsigned short* __restrict__ out_bf, float* __restrict__ out_f,
          float* __restrict__ hn, float* __restrict__ cn) {
  __shared__ __align__(16) char lds[81920];

  const int dir = blockIdx.z;
  const unsigned short* __restrict__ Wp = dir ? WpB : WpF;
  const float* __restrict__ bp = dir ? bpB : bpF;
  const int bn = blockIdx.x;   // 0..15  (192-col band of Wp)
  const int bm = blockIdx.y;   // 0..127 (128-row band of A)

  const int tid  = threadIdx.x;
  const int wid  = tid >> 6;
  const int lane = tid & 63;
  const int wm   = wid >> 1;   // 0..1
  const int wn   = wid & 1;    // 0..1

  const int  nt = K >> 6;
  const long K2 = (long)K * 2;

  // ---- staging constants (linear LDS dest, pre-swizzled global source) ----
  const int rlane = lane >> 3;                       // row within slot 0..7
  const int cb    = (((lane & 7) ^ rlane) << 4);     // pre-swizzled col byte
  const char* Asrc = (const char*)A  + ((long)bm * 128 + rlane) * K2 + cb;
  const char* Bsrc = (const char*)Wp + ((long)bn * 192 + rlane) * K2 + cb;

  // ---- compute-side constants (swizzled ds_read) ----
  const int l15 = lane & 15;
  const int hi  = lane >> 4;                  // 0..3
  const int c0  = ((hi ^ (l15 & 7)) << 4);    // kh0 chunk; kh1 = c0 ^ 64
  const int aro = (wm * 64 + l15) * 128;            // + mf*2048
  const int bro = 16384 + (wn * 96 + l15) * 128;    // + nf*2048

  f32x4 acc[4][6];
  const f32x4 zero = {0.f, 0.f, 0.f, 0.f};
#pragma unroll
  for (int i = 0; i < 4; ++i)
#pragma unroll
    for (int j = 0; j < 6; ++j) acc[i][j] = zero;

  auto STAGE = [&](int t) {   // 10 x global_load_lds per thread
    if (t >= nt) return;
    char* d = lds + (t & 1) * 40960;
    const long off = (long)t * 128;   // 64 bf16 = 128 B per K-tile
#pragma unroll
    for (int s = 0; s < 4; ++s) {
      const int slot = s * 4 + wid;
      load_lds16(Asrc + (long)(slot * 8) * K2 + off, d + slot * 1024);
    }
#pragma unroll
    for (int s = 0; s < 6; ++s) {
      const int slot = s * 4 + wid;
      load_lds16(Bsrc + (long)(slot * 8) * K2 + off, d + 16384 + slot * 1024);
    }
  };

  bf16x8 pa[4], pb[6], qa[4], qb[6];

#define READF(AR, BR, BUF, X) do {                                       \
    _Pragma("unroll") for (int nf = 0; nf < 6; ++nf)                     \
      BR[nf] = *(const bf16x8*)((BUF) + bro + nf * 2048 + (c0 ^ (X)));   \
    _Pragma("unroll") for (int mf = 0; mf < 4; ++mf)                     \
      AR[mf] = *(const bf16x8*)((BUF) + aro + mf * 2048 + (c0 ^ (X)));   \
  } while (0)

#define MFMA24(AR, BR) do {                                              \
    __builtin_amdgcn_s_setprio(1);                                       \
    _Pragma("unroll") for (int mf = 0; mf < 4; ++mf)                     \
      _Pragma("unroll") for (int nf = 0; nf < 6; ++nf)                   \
        acc[mf][nf] = __builtin_amdgcn_mfma_f32_16x16x32_bf16(           \
            AR[mf], BR[nf], acc[mf][nf], 0, 0, 0);                       \
    __builtin_amdgcn_s_setprio(0);                                       \
  } while (0)

  // prologue: stage tile 0; peel body(0) (kh0-read uncovered once)
  STAGE(0);
  VM0;
  BARRIER;
  {
    const char* buf = lds;
    STAGE(1);
    READF(pa, pb, buf, 0);
    SB;
    READF(qa, qb, buf, 64);
    SB;
    MFMA24(pa, pb);            // MFMA(0,kh0); covers the kh1 reads
    SB;
    LGKM0;                     // all buffer-0 reads register-complete
    VM0;                       // stage(1) resident
    BARRIER;
  }

#pragma unroll 1
  for (int t = 1; t < nt; ++t) {
    const char* buf = lds + (t & 1) * 40960;
    STAGE(t + 1);              // full-tile latency cover; target buffer's
                               // prior reads completed before entry barrier
    READF(pa, pb, buf, 0);     // R(t,kh0)
    SB;
    MFMA24(qa, qb);            // MFMA(t-1,kh1) -- covers R(t,kh0)
    SB;
    READF(qa, qb, buf, 64);    // R(t,kh1)
    SB;
    MFMA24(pa, pb);            // MFMA(t,kh0) -- covers R(t,kh1)
    SB;
    LGKM0;                     // all buffer-t reads register-complete
    VM0;                       // stage(t+1) resident
    BARRIER;
  }
  MFMA24(qa, qb);              // drain: MFMA(nt-1,kh1)

#undef READF
#undef MFMA24

  // ---- epilogue: gates -> h (and h_n/c_n rows) ----
  const int col    = l15;
  const int rbase  = hi * 4;
  const int chunk0 = bn * 4 + wn * 2;
  const int Lidx   = MODE * 2 + dir;

#pragma unroll
  for (int hg = 0; hg < 2; ++hg) {
    const int chunk  = chunk0 + hg;
    const int h      = chunk * 16 + col;
    const int outcol = dir * HID + h;
    const float bi = bp[chunk * 48 + col];
    const float bg = bp[chunk * 48 + 16 + col];
    const float bo = bp[chunk * 48 + 32 + col];
#pragma unroll
    for (int mf = 0; mf < 4; ++mf) {
#pragma unroll
      for (int r = 0; r < 4; ++r) {
        const int m = bm * 128 + wm * 64 + mf * 16 + rbase + r;
        const float iv = acc[mf][hg * 3 + 0][r] + bi;
        const float gv = acc[mf][hg * 3 + 1][r] + bg;
        const float ov = acc[mf][hg * 3 + 2][r] + bo;
        const float is = sigf(iv);
        const float gt = tanh_f(gv);
        const float os = sigf(ov);
        const float c  = is * gt;
        const float hv = os * tanh_f(c);
        if (MODE == 0) {
          out_bf[(long)m * 2048 + outcol] = f2b(hv);
        } else {
          out_f[(long)m * 2048 + outcol] = hv;
        }
        const bool wst = (dir == 0) ? (m >= (S_LEN - 1) * BATCH) : (m < BATCH);
        if (wst) {
          const int b = (dir == 0) ? (m - (S_LEN - 1) * BATCH) : m;
          hn[((long)Lidx * BATCH + b) * HID + h] = hv;
          cn[((long)Lidx * BATCH + b) * HID + h] = c;
        }
      }
    }
  }
}

extern "C" void kernel_launch(void* const* d_in, const int* in_sizes, int n_in,
                              void* d_out, int out_size, void* d_ws, size_t ws_size,
                              hipStream_t stream) {
  const float* x    = (const float*)d_in[0];
  const float* W_f0 = (const float*)d_in[1];
  const float* b_f0 = (const float*)d_in[2];
  const float* W_b0 = (const float*)d_in[3];
  const float* b_b0 = (const float*)d_in[4];
  const float* W_f1 = (const float*)d_in[5];
  const float* b_f1 = (const float*)d_in[6];
  const float* W_b1 = (const float*)d_in[7];
  const float* b_b1 = (const float*)d_in[8];

  float* out = (float*)d_out;
  float* hn  = out + (long)MROWS * 2048;
  float* cn  = hn + 4 * BATCH * HID;

  unsigned short* x_bf  = (unsigned short*)d_ws;
  unsigned short* out1  = x_bf + (long)MROWS * 1024;
  unsigned short* wp_f0 = out1 + (long)MROWS * 2048;
  unsigned short* wp_b0 = wp_f0 + (long)NP * 1024;
  unsigned short* wp_f1 = wp_b0 + (long)NP * 1024;
  unsigned short* wp_b1 = wp_f1 + (long)NP * 2048;
  float* bp_f0 = (float*)(wp_b1 + (long)NP * 2048);
  float* bp_b0 = bp_f0 + NP;
  float* bp_f1 = bp_b0 + NP;
  float* bp_b1 = bp_f1 + NP;

  prep<<<34864, 256, 0, stream>>>(x, x_bf, W_f0, W_b0, W_f1, W_b1,
                                  wp_f0, wp_b0, wp_f1, wp_b1,
                                  b_f0, b_b0, b_f1, b_b1,
                                  bp_f0, bp_b0, bp_f1, bp_b1);

  dim3 grid(16, 128, 2);
  lstm_gemm<0><<<grid, 256, 0, stream>>>(x_bf, wp_f0, wp_b0, bp_f0, bp_b0, 1024,
                                         out1, nullptr, hn, cn);
  lstm_gemm<1><<<grid, 256, 0, stream>>>(out1, wp_f1, wp_b1, bp_f1, bp_b1, 2048,
                                         nullptr, out, hn, cn);
}